// Round 9
// baseline (186.646 us; speedup 1.0000x reference)
//
#include <hip/hip_runtime.h>
#include <math.h>

#define HD 512
#define BB 4
#define TT 128
#define SS 512
#define LDP 40

typedef __attribute__((ext_vector_type(8))) short short8;
typedef __attribute__((ext_vector_type(4))) float floatx4;
typedef _Float16 half2_t __attribute__((ext_vector_type(2)));
typedef unsigned short ushort_t;
typedef unsigned int uint_t;

__device__ __forceinline__ float tanh_e(float x) {
    float t = __builtin_amdgcn_rcpf(__expf(2.f * x) + 1.f);
    return fmaf(-2.f, t, 1.f);
}
__device__ __forceinline__ ushort_t f2bf(float x) {      // RNE fp32->bf16
    unsigned int u = __float_as_uint(x);
    u += 0x7fffu + ((u >> 16) & 1u);
    return (ushort_t)(u >> 16);
}

// ---- Kernel 1: MFMA proj with in-staging fp32->bf16 convert + W transpose.
//  (round-7 version, proven) 4 GEMM families (grid 80 x 8):
//   bm  0..7 : tqa  = {tanh(q@Ws), v*tanh(q@Ws)}  fp32 pairs
//   bm 8..39 : peT  = fp16(tanh(enc@Wh))^T  (B,H,S)
//   bm 40..71: encWo= fp16(enc@Wo_a)        (B,S,H) row-major
//   bm 72..79: qWob = fp32(q@Wo_b)          (B*T,H)
__global__ __launch_bounds__(256) void proj_kernel(
    const float* __restrict__ query, const float* __restrict__ enc,
    const float* __restrict__ Ws, const float* __restrict__ Wh,
    const float* __restrict__ Wo, const float* __restrict__ v,
    float2* __restrict__ tqa, _Float16* __restrict__ peT,
    _Float16* __restrict__ encWo, float* __restrict__ qWob)
{
    const int bm = blockIdx.x;            // 0..79
    const int bn = blockIdx.y;            // 0..7
    int type; const float* A; const float* Bw; int m0;
    if (bm < 8)       { type = 0; A = query; Bw = Ws;                    m0 = bm * 64;        }
    else if (bm < 40) { type = 1; A = enc;   Bw = Wh;                    m0 = (bm - 8) * 64;  }
    else if (bm < 72) { type = 2; A = enc;   Bw = Wo;                    m0 = (bm - 40) * 64; }
    else              { type = 3; A = query; Bw = Wo + (size_t)512 * HD; m0 = (bm - 72) * 64; }
    const int n0 = bn * 64;

    __shared__ ushort_t As[64 * LDP];     // [m][k]
    __shared__ ushort_t Bs[64 * LDP];     // [n][k] (transposed W)

    const int tid = threadIdx.x;
    const int lane = tid & 63, w = tid >> 6;
    const int quad = lane >> 4, lrow = lane & 15;
    const int mw = (w & 1) * 32, nw = (w >> 1) * 32;

    const int am = tid >> 2, ak = (tid & 3) * 8;      // A: 8 contig k of row am
    const int bn_ = tid & 63, bkq = tid >> 6;         // B: 8 k-strided of col bn_

    floatx4 zero = {0.f, 0.f, 0.f, 0.f};
    floatx4 acc[2][2] = {{zero, zero}, {zero, zero}};

    // prefetch k0 = 0
    float4 a0 = *(const float4*)(A + (size_t)(m0 + am) * HD + ak);
    float4 a1 = *(const float4*)(A + (size_t)(m0 + am) * HD + ak + 4);
    float bv0, bv1, bv2, bv3, bv4, bv5, bv6, bv7;
    {
        const float* bp = Bw + (size_t)(bkq * 8) * HD + n0 + bn_;
        bv0 = bp[0 * HD]; bv1 = bp[1 * HD]; bv2 = bp[2 * HD]; bv3 = bp[3 * HD];
        bv4 = bp[4 * HD]; bv5 = bp[5 * HD]; bv6 = bp[6 * HD]; bv7 = bp[7 * HD];
    }

    for (int k0 = 0; k0 < HD; k0 += 32) {
        __syncthreads();
        {
            uint4 apk;
            apk.x = (uint_t)f2bf(a0.x) | ((uint_t)f2bf(a0.y) << 16);
            apk.y = (uint_t)f2bf(a0.z) | ((uint_t)f2bf(a0.w) << 16);
            apk.z = (uint_t)f2bf(a1.x) | ((uint_t)f2bf(a1.y) << 16);
            apk.w = (uint_t)f2bf(a1.z) | ((uint_t)f2bf(a1.w) << 16);
            *(uint4*)&As[am * LDP + ak] = apk;
            uint4 bpk;
            bpk.x = (uint_t)f2bf(bv0) | ((uint_t)f2bf(bv1) << 16);
            bpk.y = (uint_t)f2bf(bv2) | ((uint_t)f2bf(bv3) << 16);
            bpk.z = (uint_t)f2bf(bv4) | ((uint_t)f2bf(bv5) << 16);
            bpk.w = (uint_t)f2bf(bv6) | ((uint_t)f2bf(bv7) << 16);
            *(uint4*)&Bs[bn_ * LDP + bkq * 8] = bpk;
        }
        __syncthreads();
        if (k0 + 32 < HD) {
            a0 = *(const float4*)(A + (size_t)(m0 + am) * HD + k0 + 32 + ak);
            a1 = *(const float4*)(A + (size_t)(m0 + am) * HD + k0 + 32 + ak + 4);
            const float* bp = Bw + (size_t)(k0 + 32 + bkq * 8) * HD + n0 + bn_;
            bv0 = bp[0 * HD]; bv1 = bp[1 * HD]; bv2 = bp[2 * HD]; bv3 = bp[3 * HD];
            bv4 = bp[4 * HD]; bv5 = bp[5 * HD]; bv6 = bp[6 * HD]; bv7 = bp[7 * HD];
        }
        short8 af[2], bf[2];
        #pragma unroll
        for (int i = 0; i < 2; ++i)
            af[i] = *(const short8*)&As[(mw + i * 16 + lrow) * LDP + quad * 8];
        #pragma unroll
        for (int j = 0; j < 2; ++j)
            bf[j] = *(const short8*)&Bs[(nw + j * 16 + lrow) * LDP + quad * 8];
        #pragma unroll
        for (int i = 0; i < 2; ++i)
            #pragma unroll
            for (int j = 0; j < 2; ++j)
                acc[i][j] = __builtin_amdgcn_mfma_f32_16x16x32_bf16(af[i], bf[j], acc[i][j], 0, 0, 0);
    }

    if (type == 0) {
        #pragma unroll
        for (int j = 0; j < 2; ++j) {
            const int col = n0 + nw + j * 16 + lrow;
            const float vj = v[col];
            #pragma unroll
            for (int i = 0; i < 2; ++i)
                #pragma unroll
                for (int r = 0; r < 4; ++r) {
                    const int row = m0 + mw + i * 16 + quad * 4 + r;
                    float tq = tanh_e(acc[i][j][r]);
                    float2 o; o.x = tq; o.y = vj * tq;
                    tqa[(size_t)row * HD + col] = o;
                }
        }
    } else if (type == 1) {
        #pragma unroll
        for (int i = 0; i < 2; ++i)
            #pragma unroll
            for (int j = 0; j < 2; ++j) {
                const int gm = m0 + mw + i * 16 + quad * 4;
                const int b = gm >> 9, s = gm & 511;
                const int col = n0 + nw + j * 16 + lrow;
                _Float16 t0 = (_Float16)tanh_e(acc[i][j][0]);
                _Float16 t1 = (_Float16)tanh_e(acc[i][j][1]);
                _Float16 t2 = (_Float16)tanh_e(acc[i][j][2]);
                _Float16 t3 = (_Float16)tanh_e(acc[i][j][3]);
                ushort4 o;
                o.x = *(ushort_t*)&t0; o.y = *(ushort_t*)&t1;
                o.z = *(ushort_t*)&t2; o.w = *(ushort_t*)&t3;
                *(ushort4*)((ushort_t*)peT + ((size_t)b * HD + col) * SS + s) = o;
            }
    } else if (type == 2) {
        #pragma unroll
        for (int i = 0; i < 2; ++i)
            #pragma unroll
            for (int j = 0; j < 2; ++j) {
                const int col = n0 + nw + j * 16 + lrow;
                #pragma unroll
                for (int r = 0; r < 4; ++r) {
                    const int gm = m0 + mw + i * 16 + quad * 4 + r;
                    encWo[(size_t)gm * HD + col] = (_Float16)acc[i][j][r];
                }
            }
    } else {
        #pragma unroll
        for (int i = 0; i < 2; ++i)
            #pragma unroll
            for (int j = 0; j < 2; ++j) {
                const int col = n0 + nw + j * 16 + lrow;
                #pragma unroll
                for (int r = 0; r < 4; ++r) {
                    const int gm = m0 + mw + i * 16 + quad * 4 + r;
                    qWob[(size_t)gm * HD + col] = acc[i][j][r];
                }
            }
    }
}

// ---- Kernel 2: fused score + softmax + output. One block (1024 thr) per t-PAIR.
//  Round-7 body (LDS broadcast table) + XCD-batch swizzle (pins each batch's
//  1 MB peT+encWo slab to one XCD pair's L2) + full unroll on phase A's h-loop
//  (exposes all 32 peT loads for deep prefetch; VGPR budget 128 at 4 waves/EU).
__global__ __launch_bounds__(1024, 4) void fused_kernel(
    const float2* __restrict__ tqa, const _Float16* __restrict__ peT,
    const float* __restrict__ vv, const _Float16* __restrict__ encWo,
    const float* __restrict__ qWob, const int* __restrict__ lens,
    float* __restrict__ out)
{
    const int bid = blockIdx.x;                   // 0..255
    const int b = (bid >> 1) & 3;                 // XCD pair -> batch (bijective)
    const int pr = ((bid >> 3) << 1) | (bid & 1); // 0..63 pair within batch
    const int bt0 = b * TT + pr * 2;              // pair (bt0, bt0+1)
    const int tid = threadIdx.x;                  // 0..1023
    const int lane = tid & 63, wid = tid >> 6;    // wid 0..15
    const int len = lens[b];

    __shared__ uint4  s_tab[2][HD];               // 16 KB {tq2,v2,vt2,-} per t
    __shared__ float  s_part[16][2][SS];          // 64 KB combine slabs (A: 16, C: 8)
    __shared__ float  s_sc[2][SS];                // 4 KB scores
    __shared__ uint_t s_al2[SS][2];               // 4 KB fp16 alpha pairs [s][t]
    __shared__ float  s_red[32];

    {
        const int t_loc = tid >> 9, h = tid & 511;
        float2 q = tqa[(size_t)(bt0 + t_loc) * HD + h];
        float vh = vv[h];
        _Float16 tqh = (_Float16)q.x, vvh = (_Float16)vh, vth = (_Float16)q.y;
        uint_t ta = *(ushort_t*)&tqh, tb = *(ushort_t*)&vvh, tc = *(ushort_t*)&vth;
        uint4 e4; e4.x = ta | (ta << 16); e4.y = tb | (tb << 16); e4.z = tc | (tc << 16); e4.w = 0;
        s_tab[t_loc][h] = e4;
    }
    __syncthreads();

    // ---- phase A: thread = (sg: 8 s) x (slice wid: 32 h) x 2 t ----
    const int sg = tid & 63;
    const int hq = (tid >> 6) & 7, sub = tid >> 9;
    const int s0 = sg * 8;
    const int hbase = hq * 64 + sub * 32;
    float p0[8] = {0.f,0.f,0.f,0.f,0.f,0.f,0.f,0.f};
    float p1[8] = {0.f,0.f,0.f,0.f,0.f,0.f,0.f,0.f};
    if (s0 < len) {
        const ushort_t* colp = (const ushort_t*)peT + ((size_t)b * HD + hbase) * SS + s0;
        const uint4* tp0 = &s_tab[0][hbase];
        const uint4* tp1 = &s_tab[1][hbase];
        half2_t one2; one2[0] = (_Float16)1.f; one2[1] = (_Float16)1.f;
        #pragma unroll
        for (int i = 0; i < 16; ++i) {            // 2 h per iter, fully unrolled
            uint4 pA = *(const uint4*)(colp + (size_t)(2 * i) * SS);
            uint4 pB = *(const uint4*)(colp + (size_t)(2 * i + 1) * SS);
            uint4 cA0 = tp0[2 * i], cB0 = tp0[2 * i + 1];
            uint4 cA1 = tp1[2 * i], cB1 = tp1[2 * i + 1];
            half2_t teA0 = *(half2_t*)&pA.x, teA1 = *(half2_t*)&pA.y;
            half2_t teA2 = *(half2_t*)&pA.z, teA3 = *(half2_t*)&pA.w;
            half2_t teB0 = *(half2_t*)&pB.x, teB1 = *(half2_t*)&pB.y;
            half2_t teB2 = *(half2_t*)&pB.z, teB3 = *(half2_t*)&pB.w;
            {
                half2_t tqA = *(half2_t*)&cA0.x, vA = *(half2_t*)&cA0.y, vtA = *(half2_t*)&cA0.z;
                half2_t tqB = *(half2_t*)&cB0.x, vB = *(half2_t*)&cB0.y, vtB = *(half2_t*)&cB0.z;
                half2_t dA0 = tqA * teA0 + one2, dA1 = tqA * teA1 + one2;
                half2_t dA2 = tqA * teA2 + one2, dA3 = tqA * teA3 + one2;
                half2_t dB0 = tqB * teB0 + one2, dB1 = tqB * teB1 + one2;
                half2_t dB2 = tqB * teB2 + one2, dB3 = tqB * teB3 + one2;
                half2_t mA0 = vA * teA0 + vtA, mA1 = vA * teA1 + vtA;
                half2_t mA2 = vA * teA2 + vtA, mA3 = vA * teA3 + vtA;
                half2_t mB0 = vB * teB0 + vtB, mB1 = vB * teB1 + vtB;
                half2_t mB2 = vB * teB2 + vtB, mB3 = vB * teB3 + vtB;
                half2_t n0h = mA0 * dB0 + mB0 * dA0, n1h = mA1 * dB1 + mB1 * dA1;
                half2_t n2h = mA2 * dB2 + mB2 * dA2, n3h = mA3 * dB3 + mB3 * dA3;
                half2_t d0h = dA0 * dB0, d1h = dA1 * dB1;
                half2_t d2h = dA2 * dB2, d3h = dA3 * dB3;
                p0[0] = fmaf((float)n0h[0], __builtin_amdgcn_rcpf((float)d0h[0]), p0[0]);
                p0[1] = fmaf((float)n0h[1], __builtin_amdgcn_rcpf((float)d0h[1]), p0[1]);
                p0[2] = fmaf((float)n1h[0], __builtin_amdgcn_rcpf((float)d1h[0]), p0[2]);
                p0[3] = fmaf((float)n1h[1], __builtin_amdgcn_rcpf((float)d1h[1]), p0[3]);
                p0[4] = fmaf((float)n2h[0], __builtin_amdgcn_rcpf((float)d2h[0]), p0[4]);
                p0[5] = fmaf((float)n2h[1], __builtin_amdgcn_rcpf((float)d2h[1]), p0[5]);
                p0[6] = fmaf((float)n3h[0], __builtin_amdgcn_rcpf((float)d3h[0]), p0[6]);
                p0[7] = fmaf((float)n3h[1], __builtin_amdgcn_rcpf((float)d3h[1]), p0[7]);
            }
            {
                half2_t tqA = *(half2_t*)&cA1.x, vA = *(half2_t*)&cA1.y, vtA = *(half2_t*)&cA1.z;
                half2_t tqB = *(half2_t*)&cB1.x, vB = *(half2_t*)&cB1.y, vtB = *(half2_t*)&cB1.z;
                half2_t dA0 = tqA * teA0 + one2, dA1 = tqA * teA1 + one2;
                half2_t dA2 = tqA * teA2 + one2, dA3 = tqA * teA3 + one2;
                half2_t dB0 = tqB * teB0 + one2, dB1 = tqB * teB1 + one2;
                half2_t dB2 = tqB * teB2 + one2, dB3 = tqB * teB3 + one2;
                half2_t mA0 = vA * teA0 + vtA, mA1 = vA * teA1 + vtA;
                half2_t mA2 = vA * teA2 + vtA, mA3 = vA * teA3 + vtA;
                half2_t mB0 = vB * teB0 + vtB, mB1 = vB * teB1 + vtB;
                half2_t mB2 = vB * teB2 + vtB, mB3 = vB * teB3 + vtB;
                half2_t n0h = mA0 * dB0 + mB0 * dA0, n1h = mA1 * dB1 + mB1 * dA1;
                half2_t n2h = mA2 * dB2 + mB2 * dA2, n3h = mA3 * dB3 + mB3 * dA3;
                half2_t d0h = dA0 * dB0, d1h = dA1 * dB1;
                half2_t d2h = dA2 * dB2, d3h = dA3 * dB3;
                p1[0] = fmaf((float)n0h[0], __builtin_amdgcn_rcpf((float)d0h[0]), p1[0]);
                p1[1] = fmaf((float)n0h[1], __builtin_amdgcn_rcpf((float)d0h[1]), p1[1]);
                p1[2] = fmaf((float)n1h[0], __builtin_amdgcn_rcpf((float)d1h[0]), p1[2]);
                p1[3] = fmaf((float)n1h[1], __builtin_amdgcn_rcpf((float)d1h[1]), p1[3]);
                p1[4] = fmaf((float)n2h[0], __builtin_amdgcn_rcpf((float)d2h[0]), p1[4]);
                p1[5] = fmaf((float)n2h[1], __builtin_amdgcn_rcpf((float)d2h[1]), p1[5]);
                p1[6] = fmaf((float)n3h[0], __builtin_amdgcn_rcpf((float)d3h[0]), p1[6]);
                p1[7] = fmaf((float)n3h[1], __builtin_amdgcn_rcpf((float)d3h[1]), p1[7]);
            }
        }
    }
    {
        float4 w0; w0.x = p0[0]; w0.y = p0[1]; w0.z = p0[2]; w0.w = p0[3];
        float4 w1; w1.x = p0[4]; w1.y = p0[5]; w1.z = p0[6]; w1.w = p0[7];
        *(float4*)&s_part[wid][0][s0]     = w0;
        *(float4*)&s_part[wid][0][s0 + 4] = w1;
        float4 w2; w2.x = p1[0]; w2.y = p1[1]; w2.z = p1[2]; w2.w = p1[3];
        float4 w3; w3.x = p1[4]; w3.y = p1[5]; w3.z = p1[6]; w3.w = p1[7];
        *(float4*)&s_part[wid][1][s0]     = w2;
        *(float4*)&s_part[wid][1][s0 + 4] = w3;
    }
    __syncthreads();
    {
        const int t_loc = tid >> 9, s = tid & 511;
        float acc = 0.f;
        #pragma unroll
        for (int q = 0; q < 16; ++q) acc += s_part[q][t_loc][s];
        s_sc[t_loc][s] = (s < len) ? acc : -INFINITY;
    }
    __syncthreads();

    {
        const int t_loc = tid >> 9;
        float sc = s_sc[t_loc][tid & 511];
        float m = sc;
        #pragma unroll
        for (int off = 32; off; off >>= 1) m = fmaxf(m, __shfl_xor(m, off, 64));
        if (lane == 0) s_red[wid] = m;
        __syncthreads();
        const int rb = (t_loc << 3);
        m = s_red[rb];
        #pragma unroll
        for (int i2 = 1; i2 < 8; ++i2) m = fmaxf(m, s_red[rb + i2]);

        float e = __expf(sc - m);                 // exp(-inf)=0 handles mask
        float sum = e;
        #pragma unroll
        for (int off = 32; off; off >>= 1) sum += __shfl_xor(sum, off, 64);
        if (lane == 0) s_red[16 + wid] = sum;
        __syncthreads();
        float total = s_red[16 + rb];
        #pragma unroll
        for (int i2 = 1; i2 < 8; ++i2) total += s_red[16 + rb + i2];
        float a = e * __builtin_amdgcn_rcpf(total);
        _Float16 ah = (_Float16)a;
        uint_t ap = *(ushort_t*)&ah;
        s_al2[tid & 511][t_loc] = ap | (ap << 16);   // 0 past len
    }
    __syncthreads();

    const int ng = tid & 127, sq = tid >> 7;      // sq 0..7
    const int n0 = ng * 4;
    const int sbeg = sq * 64;
    float fo0[4] = {0.f, 0.f, 0.f, 0.f};
    float fo1[4] = {0.f, 0.f, 0.f, 0.f};
    {
        const ushort_t* ew = (const ushort_t*)encWo + ((size_t)b * SS + sbeg) * HD + n0;
        const int rem = (len > sbeg) ? ((len - sbeg < 64) ? len - sbeg : 64) : 0;
        const int schunks = (rem + 7) >> 3;       // alpha==0 past len -> full chunks safe
        for (int c = 0; c < schunks; ++c) {
            half2_t a01_0, a23_0, a01_1, a23_1;
            a01_0[0] = (_Float16)0.f; a01_0[1] = (_Float16)0.f;
            a23_0 = a01_0; a01_1 = a01_0; a23_1 = a01_0;
            const ushort_t* ewc = ew + (size_t)(c * 8) * HD;
            #pragma unroll
            for (int k = 0; k < 8; ++k) {
                uint2 wv = *(const uint2*)(ewc + (size_t)k * HD);
                uint2 av = *(const uint2*)&s_al2[sbeg + c * 8 + k][0];
                half2_t w01 = *(half2_t*)&wv.x, w23 = *(half2_t*)&wv.y;
                half2_t al0 = *(half2_t*)&av.x, al1 = *(half2_t*)&av.y;
                a01_0 = al0 * w01 + a01_0; a23_0 = al0 * w23 + a23_0;
                a01_1 = al1 * w01 + a01_1; a23_1 = al1 * w23 + a23_1;
            }
            fo0[0] += (float)a01_0[0]; fo0[1] += (float)a01_0[1];
            fo0[2] += (float)a23_0[0]; fo0[3] += (float)a23_0[1];
            fo1[0] += (float)a01_1[0]; fo1[1] += (float)a01_1[1];
            fo1[2] += (float)a23_1[0]; fo1[3] += (float)a23_1[1];
        }
    }
    __syncthreads();                              // s_part reuse barrier
    {
        float4 w0; w0.x = fo0[0]; w0.y = fo0[1]; w0.z = fo0[2]; w0.w = fo0[3];
        float4 w1; w1.x = fo1[0]; w1.y = fo1[1]; w1.z = fo1[2]; w1.w = fo1[3];
        *(float4*)&s_part[sq][0][n0] = w0;
        *(float4*)&s_part[sq][1][n0] = w1;
    }
    __syncthreads();
    {
        const int t_loc = tid >> 9, n = tid & 511;
        float acc = 0.f;
        #pragma unroll
        for (int q = 0; q < 8; ++q) acc += s_part[q][t_loc][n];
        acc += qWob[(size_t)(bt0 + t_loc) * HD + n];
        out[(size_t)(bt0 + t_loc) * HD + n] = tanh_e(acc);
    }
}

extern "C" void kernel_launch(void* const* d_in, const int* in_sizes, int n_in,
                              void* d_out, int out_size, void* d_ws, size_t ws_size,
                              hipStream_t stream) {
    (void)in_sizes; (void)n_in; (void)out_size; (void)ws_size;
    const float* query = (const float*)d_in[0];   // (B,T,H)
    const float* enc   = (const float*)d_in[1];   // (B,S,H)
    const int*   lens  = (const int*)d_in[2];     // (B,)
    const float* W_h   = (const float*)d_in[3];   // (H,H)
    const float* W_s   = (const float*)d_in[4];   // (H,H)
    const float* v     = (const float*)d_in[5];   // (H,)
    const float* W_out = (const float*)d_in[6];   // (2H,H)
    float* out = (float*)d_out;

    // workspace layout (~7 MB)
    float2*   tqa   = (float2*)d_ws;                            // 2 MB {tanh(pq), v*tanh(pq)}
    _Float16* peT   = (_Float16*)(tqa + (size_t)BB * TT * HD);  // 2 MB fp16 tanh(pe)^T
    _Float16* encWo = peT + (size_t)BB * HD * SS;               // 2 MB fp16 enc@Wo_a
    float*    qWob  = (float*)(encWo + (size_t)BB * SS * HD);   // 1 MB fp32 q@Wo_b

    proj_kernel<<<dim3(80, 8), 256, 0, stream>>>(query, enc, W_s, W_h, W_out, v,
                                                 tqa, peT, encWo, qWob);
    fused_kernel<<<dim3(BB * TT / 2), 1024, 0, stream>>>(tqa, peT, v, encWo, qWob, lens, out);
}

// Round 10
// 109.877 us; speedup vs baseline: 1.6987x; 1.6987x over previous
//
#include <hip/hip_runtime.h>
#include <math.h>

#define HD 512
#define BB 4
#define TT 128
#define SS 512
#define LDP 40

typedef __attribute__((ext_vector_type(8))) short short8;
typedef __attribute__((ext_vector_type(4))) float floatx4;
typedef _Float16 half2_t __attribute__((ext_vector_type(2)));
typedef unsigned short ushort_t;
typedef unsigned int uint_t;

__device__ __forceinline__ float tanh_e(float x) {
    float t = __builtin_amdgcn_rcpf(__expf(2.f * x) + 1.f);
    return fmaf(-2.f, t, 1.f);
}
__device__ __forceinline__ ushort_t f2bf(float x) {      // RNE fp32->bf16
    unsigned int u = __float_as_uint(x);
    u += 0x7fffu + ((u >> 16) & 1u);
    return (ushort_t)(u >> 16);
}

// ---- Kernel 1: MFMA proj with in-staging fp32->bf16 convert + W transpose.
//  Reads query/enc/W directly (no prep kernel). 4 GEMM families (grid 80 x 8):
//   bm  0..7 : tqa  = {tanh(q@Ws), v*tanh(q@Ws)}  fp32 pairs
//   bm 8..39 : peT  = fp16(tanh(enc@Wh))^T  (B,H,S)
//   bm 40..71: encWo= fp16(enc@Wo_a)        (B,S,H) row-major
//   bm 72..79: qWob = fp32(q@Wo_b)          (B*T,H)
//  A staging: fp32 row-major [m][k] -> cvt -> As[m][k].
//  B staging: W is [k][n]; thread owns (n = tid&63, kq = tid>>6): reads 8
//  k-strided floats of column n0+n (coalesced across lanes), packs one uint4,
//  writes transposed Bs[n][kq*8..+7].
__global__ __launch_bounds__(256) void proj_kernel(
    const float* __restrict__ query, const float* __restrict__ enc,
    const float* __restrict__ Ws, const float* __restrict__ Wh,
    const float* __restrict__ Wo, const float* __restrict__ v,
    float2* __restrict__ tqa, _Float16* __restrict__ peT,
    _Float16* __restrict__ encWo, float* __restrict__ qWob)
{
    const int bm = blockIdx.x;            // 0..79
    const int bn = blockIdx.y;            // 0..7
    int type; const float* A; const float* Bw; int m0;
    if (bm < 8)       { type = 0; A = query; Bw = Ws;                    m0 = bm * 64;        }
    else if (bm < 40) { type = 1; A = enc;   Bw = Wh;                    m0 = (bm - 8) * 64;  }
    else if (bm < 72) { type = 2; A = enc;   Bw = Wo;                    m0 = (bm - 40) * 64; }
    else              { type = 3; A = query; Bw = Wo + (size_t)512 * HD; m0 = (bm - 72) * 64; }
    const int n0 = bn * 64;

    __shared__ ushort_t As[64 * LDP];     // [m][k]
    __shared__ ushort_t Bs[64 * LDP];     // [n][k] (transposed W)

    const int tid = threadIdx.x;
    const int lane = tid & 63, w = tid >> 6;
    const int quad = lane >> 4, lrow = lane & 15;
    const int mw = (w & 1) * 32, nw = (w >> 1) * 32;

    const int am = tid >> 2, ak = (tid & 3) * 8;      // A: 8 contig k of row am
    const int bn_ = tid & 63, bkq = tid >> 6;         // B: 8 k-strided of col bn_

    floatx4 zero = {0.f, 0.f, 0.f, 0.f};
    floatx4 acc[2][2] = {{zero, zero}, {zero, zero}};

    // prefetch k0 = 0
    float4 a0 = *(const float4*)(A + (size_t)(m0 + am) * HD + ak);
    float4 a1 = *(const float4*)(A + (size_t)(m0 + am) * HD + ak + 4);
    float bv0, bv1, bv2, bv3, bv4, bv5, bv6, bv7;
    {
        const float* bp = Bw + (size_t)(bkq * 8) * HD + n0 + bn_;
        bv0 = bp[0 * HD]; bv1 = bp[1 * HD]; bv2 = bp[2 * HD]; bv3 = bp[3 * HD];
        bv4 = bp[4 * HD]; bv5 = bp[5 * HD]; bv6 = bp[6 * HD]; bv7 = bp[7 * HD];
    }

    for (int k0 = 0; k0 < HD; k0 += 32) {
        __syncthreads();
        {
            uint4 apk;
            apk.x = (uint_t)f2bf(a0.x) | ((uint_t)f2bf(a0.y) << 16);
            apk.y = (uint_t)f2bf(a0.z) | ((uint_t)f2bf(a0.w) << 16);
            apk.z = (uint_t)f2bf(a1.x) | ((uint_t)f2bf(a1.y) << 16);
            apk.w = (uint_t)f2bf(a1.z) | ((uint_t)f2bf(a1.w) << 16);
            *(uint4*)&As[am * LDP + ak] = apk;
            uint4 bpk;
            bpk.x = (uint_t)f2bf(bv0) | ((uint_t)f2bf(bv1) << 16);
            bpk.y = (uint_t)f2bf(bv2) | ((uint_t)f2bf(bv3) << 16);
            bpk.z = (uint_t)f2bf(bv4) | ((uint_t)f2bf(bv5) << 16);
            bpk.w = (uint_t)f2bf(bv6) | ((uint_t)f2bf(bv7) << 16);
            *(uint4*)&Bs[bn_ * LDP + bkq * 8] = bpk;
        }
        __syncthreads();
        if (k0 + 32 < HD) {
            a0 = *(const float4*)(A + (size_t)(m0 + am) * HD + k0 + 32 + ak);
            a1 = *(const float4*)(A + (size_t)(m0 + am) * HD + k0 + 32 + ak + 4);
            const float* bp = Bw + (size_t)(k0 + 32 + bkq * 8) * HD + n0 + bn_;
            bv0 = bp[0 * HD]; bv1 = bp[1 * HD]; bv2 = bp[2 * HD]; bv3 = bp[3 * HD];
            bv4 = bp[4 * HD]; bv5 = bp[5 * HD]; bv6 = bp[6 * HD]; bv7 = bp[7 * HD];
        }
        short8 af[2], bf[2];
        #pragma unroll
        for (int i = 0; i < 2; ++i)
            af[i] = *(const short8*)&As[(mw + i * 16 + lrow) * LDP + quad * 8];
        #pragma unroll
        for (int j = 0; j < 2; ++j)
            bf[j] = *(const short8*)&Bs[(nw + j * 16 + lrow) * LDP + quad * 8];
        #pragma unroll
        for (int i = 0; i < 2; ++i)
            #pragma unroll
            for (int j = 0; j < 2; ++j)
                acc[i][j] = __builtin_amdgcn_mfma_f32_16x16x32_bf16(af[i], bf[j], acc[i][j], 0, 0, 0);
    }

    if (type == 0) {
        #pragma unroll
        for (int j = 0; j < 2; ++j) {
            const int col = n0 + nw + j * 16 + lrow;
            const float vj = v[col];
            #pragma unroll
            for (int i = 0; i < 2; ++i)
                #pragma unroll
                for (int r = 0; r < 4; ++r) {
                    const int row = m0 + mw + i * 16 + quad * 4 + r;
                    float tq = tanh_e(acc[i][j][r]);
                    float2 o; o.x = tq; o.y = vj * tq;
                    tqa[(size_t)row * HD + col] = o;
                }
        }
    } else if (type == 1) {
        #pragma unroll
        for (int i = 0; i < 2; ++i)
            #pragma unroll
            for (int j = 0; j < 2; ++j) {
                const int gm = m0 + mw + i * 16 + quad * 4;
                const int b = gm >> 9, s = gm & 511;
                const int col = n0 + nw + j * 16 + lrow;
                _Float16 t0 = (_Float16)tanh_e(acc[i][j][0]);
                _Float16 t1 = (_Float16)tanh_e(acc[i][j][1]);
                _Float16 t2 = (_Float16)tanh_e(acc[i][j][2]);
                _Float16 t3 = (_Float16)tanh_e(acc[i][j][3]);
                ushort4 o;
                o.x = *(ushort_t*)&t0; o.y = *(ushort_t*)&t1;
                o.z = *(ushort_t*)&t2; o.w = *(ushort_t*)&t3;
                *(ushort4*)((ushort_t*)peT + ((size_t)b * HD + col) * SS + s) = o;
            }
    } else if (type == 2) {
        #pragma unroll
        for (int i = 0; i < 2; ++i)
            #pragma unroll
            for (int j = 0; j < 2; ++j) {
                const int col = n0 + nw + j * 16 + lrow;
                #pragma unroll
                for (int r = 0; r < 4; ++r) {
                    const int gm = m0 + mw + i * 16 + quad * 4 + r;
                    encWo[(size_t)gm * HD + col] = (_Float16)acc[i][j][r];
                }
            }
    } else {
        #pragma unroll
        for (int i = 0; i < 2; ++i)
            #pragma unroll
            for (int j = 0; j < 2; ++j) {
                const int col = n0 + nw + j * 16 + lrow;
                #pragma unroll
                for (int r = 0; r < 4; ++r) {
                    const int gm = m0 + mw + i * 16 + quad * 4 + r;
                    qWob[(size_t)gm * HD + col] = acc[i][j][r];
                }
            }
    }
}

// ---- Kernel 2: fused score + softmax + output. One block (1024 thr) per t-PAIR.
//  (round-7 version, proven 109.9 us path: LDS broadcast table, unroll 2,
//   marching pointer, natural blockIdx->batch mapping) ----
__global__ __launch_bounds__(1024, 4) void fused_kernel(
    const float2* __restrict__ tqa, const _Float16* __restrict__ peT,
    const float* __restrict__ vv, const _Float16* __restrict__ encWo,
    const float* __restrict__ qWob, const int* __restrict__ lens,
    float* __restrict__ out)
{
    const int bt0 = blockIdx.x * 2;               // pair (bt0, bt0+1), same batch
    const int b = bt0 >> 7;
    const int tid = threadIdx.x;                  // 0..1023
    const int lane = tid & 63, wid = tid >> 6;    // wid 0..15
    const int len = lens[b];

    __shared__ uint4  s_tab[2][HD];               // 16 KB {tq2,v2,vt2,-} per t
    __shared__ float  s_part[16][2][SS];          // 64 KB combine slabs (A: 16, C: 8)
    __shared__ float  s_sc[2][SS];                // 4 KB scores
    __shared__ uint_t s_al2[SS][2];               // 4 KB fp16 alpha pairs [s][t]
    __shared__ float  s_red[32];

    {
        const int t_loc = tid >> 9, h = tid & 511;
        float2 q = tqa[(size_t)(bt0 + t_loc) * HD + h];
        float vh = vv[h];
        _Float16 tqh = (_Float16)q.x, vvh = (_Float16)vh, vth = (_Float16)q.y;
        uint_t ta = *(ushort_t*)&tqh, tb = *(ushort_t*)&vvh, tc = *(ushort_t*)&vth;
        uint4 e4; e4.x = ta | (ta << 16); e4.y = tb | (tb << 16); e4.z = tc | (tc << 16); e4.w = 0;
        s_tab[t_loc][h] = e4;
    }
    __syncthreads();

    // ---- phase A: thread = (sg: 8 s) x (slice wid: 32 h) x 2 t ----
    const int sg = tid & 63;
    const int hq = (tid >> 6) & 7, sub = tid >> 9;
    const int s0 = sg * 8;
    const int hbase = hq * 64 + sub * 32;
    float p0[8] = {0.f,0.f,0.f,0.f,0.f,0.f,0.f,0.f};
    float p1[8] = {0.f,0.f,0.f,0.f,0.f,0.f,0.f,0.f};
    if (s0 < len) {
        const ushort_t* colp = (const ushort_t*)peT + ((size_t)b * HD + hbase) * SS + s0;
        const uint4* tp0 = &s_tab[0][hbase];
        const uint4* tp1 = &s_tab[1][hbase];
        half2_t one2; one2[0] = (_Float16)1.f; one2[1] = (_Float16)1.f;
        #pragma unroll 2
        for (int i = 0; i < 16; ++i) {            // 2 h per iter
            uint4 pA = *(const uint4*)(colp);
            uint4 pB = *(const uint4*)(colp + SS);
            colp += 2 * SS;
            uint4 cA0 = tp0[2 * i], cB0 = tp0[2 * i + 1];
            uint4 cA1 = tp1[2 * i], cB1 = tp1[2 * i + 1];
            half2_t teA0 = *(half2_t*)&pA.x, teA1 = *(half2_t*)&pA.y;
            half2_t teA2 = *(half2_t*)&pA.z, teA3 = *(half2_t*)&pA.w;
            half2_t teB0 = *(half2_t*)&pB.x, teB1 = *(half2_t*)&pB.y;
            half2_t teB2 = *(half2_t*)&pB.z, teB3 = *(half2_t*)&pB.w;
            {
                half2_t tqA = *(half2_t*)&cA0.x, vA = *(half2_t*)&cA0.y, vtA = *(half2_t*)&cA0.z;
                half2_t tqB = *(half2_t*)&cB0.x, vB = *(half2_t*)&cB0.y, vtB = *(half2_t*)&cB0.z;
                half2_t dA0 = tqA * teA0 + one2, dA1 = tqA * teA1 + one2;
                half2_t dA2 = tqA * teA2 + one2, dA3 = tqA * teA3 + one2;
                half2_t dB0 = tqB * teB0 + one2, dB1 = tqB * teB1 + one2;
                half2_t dB2 = tqB * teB2 + one2, dB3 = tqB * teB3 + one2;
                half2_t mA0 = vA * teA0 + vtA, mA1 = vA * teA1 + vtA;
                half2_t mA2 = vA * teA2 + vtA, mA3 = vA * teA3 + vtA;
                half2_t mB0 = vB * teB0 + vtB, mB1 = vB * teB1 + vtB;
                half2_t mB2 = vB * teB2 + vtB, mB3 = vB * teB3 + vtB;
                half2_t n0h = mA0 * dB0 + mB0 * dA0, n1h = mA1 * dB1 + mB1 * dA1;
                half2_t n2h = mA2 * dB2 + mB2 * dA2, n3h = mA3 * dB3 + mB3 * dA3;
                half2_t d0h = dA0 * dB0, d1h = dA1 * dB1;
                half2_t d2h = dA2 * dB2, d3h = dA3 * dB3;
                p0[0] = fmaf((float)n0h[0], __builtin_amdgcn_rcpf((float)d0h[0]), p0[0]);
                p0[1] = fmaf((float)n0h[1], __builtin_amdgcn_rcpf((float)d0h[1]), p0[1]);
                p0[2] = fmaf((float)n1h[0], __builtin_amdgcn_rcpf((float)d1h[0]), p0[2]);
                p0[3] = fmaf((float)n1h[1], __builtin_amdgcn_rcpf((float)d1h[1]), p0[3]);
                p0[4] = fmaf((float)n2h[0], __builtin_amdgcn_rcpf((float)d2h[0]), p0[4]);
                p0[5] = fmaf((float)n2h[1], __builtin_amdgcn_rcpf((float)d2h[1]), p0[5]);
                p0[6] = fmaf((float)n3h[0], __builtin_amdgcn_rcpf((float)d3h[0]), p0[6]);
                p0[7] = fmaf((float)n3h[1], __builtin_amdgcn_rcpf((float)d3h[1]), p0[7]);
            }
            {
                half2_t tqA = *(half2_t*)&cA1.x, vA = *(half2_t*)&cA1.y, vtA = *(half2_t*)&cA1.z;
                half2_t tqB = *(half2_t*)&cB1.x, vB = *(half2_t*)&cB1.y, vtB = *(half2_t*)&cB1.z;
                half2_t dA0 = tqA * teA0 + one2, dA1 = tqA * teA1 + one2;
                half2_t dA2 = tqA * teA2 + one2, dA3 = tqA * teA3 + one2;
                half2_t dB0 = tqB * teB0 + one2, dB1 = tqB * teB1 + one2;
                half2_t dB2 = tqB * teB2 + one2, dB3 = tqB * teB3 + one2;
                half2_t mA0 = vA * teA0 + vtA, mA1 = vA * teA1 + vtA;
                half2_t mA2 = vA * teA2 + vtA, mA3 = vA * teA3 + vtA;
                half2_t mB0 = vB * teB0 + vtB, mB1 = vB * teB1 + vtB;
                half2_t mB2 = vB * teB2 + vtB, mB3 = vB * teB3 + vtB;
                half2_t n0h = mA0 * dB0 + mB0 * dA0, n1h = mA1 * dB1 + mB1 * dA1;
                half2_t n2h = mA2 * dB2 + mB2 * dA2, n3h = mA3 * dB3 + mB3 * dA3;
                half2_t d0h = dA0 * dB0, d1h = dA1 * dB1;
                half2_t d2h = dA2 * dB2, d3h = dA3 * dB3;
                p1[0] = fmaf((float)n0h[0], __builtin_amdgcn_rcpf((float)d0h[0]), p1[0]);
                p1[1] = fmaf((float)n0h[1], __builtin_amdgcn_rcpf((float)d0h[1]), p1[1]);
                p1[2] = fmaf((float)n1h[0], __builtin_amdgcn_rcpf((float)d1h[0]), p1[2]);
                p1[3] = fmaf((float)n1h[1], __builtin_amdgcn_rcpf((float)d1h[1]), p1[3]);
                p1[4] = fmaf((float)n2h[0], __builtin_amdgcn_rcpf((float)d2h[0]), p1[4]);
                p1[5] = fmaf((float)n2h[1], __builtin_amdgcn_rcpf((float)d2h[1]), p1[5]);
                p1[6] = fmaf((float)n3h[0], __builtin_amdgcn_rcpf((float)d3h[0]), p1[6]);
                p1[7] = fmaf((float)n3h[1], __builtin_amdgcn_rcpf((float)d3h[1]), p1[7]);
            }
        }
    }
    {
        float4 w0; w0.x = p0[0]; w0.y = p0[1]; w0.z = p0[2]; w0.w = p0[3];
        float4 w1; w1.x = p0[4]; w1.y = p0[5]; w1.z = p0[6]; w1.w = p0[7];
        *(float4*)&s_part[wid][0][s0]     = w0;
        *(float4*)&s_part[wid][0][s0 + 4] = w1;
        float4 w2; w2.x = p1[0]; w2.y = p1[1]; w2.z = p1[2]; w2.w = p1[3];
        float4 w3; w3.x = p1[4]; w3.y = p1[5]; w3.z = p1[6]; w3.w = p1[7];
        *(float4*)&s_part[wid][1][s0]     = w2;
        *(float4*)&s_part[wid][1][s0 + 4] = w3;
    }
    __syncthreads();
    {
        const int t_loc = tid >> 9, s = tid & 511;
        float acc = 0.f;
        #pragma unroll
        for (int q = 0; q < 16; ++q) acc += s_part[q][t_loc][s];
        s_sc[t_loc][s] = (s < len) ? acc : -INFINITY;
    }
    __syncthreads();

    {
        const int t_loc = tid >> 9;
        float sc = s_sc[t_loc][tid & 511];
        float m = sc;
        #pragma unroll
        for (int off = 32; off; off >>= 1) m = fmaxf(m, __shfl_xor(m, off, 64));
        if (lane == 0) s_red[wid] = m;
        __syncthreads();
        const int rb = (t_loc << 3);
        m = s_red[rb];
        #pragma unroll
        for (int i2 = 1; i2 < 8; ++i2) m = fmaxf(m, s_red[rb + i2]);

        float e = __expf(sc - m);                 // exp(-inf)=0 handles mask
        float sum = e;
        #pragma unroll
        for (int off = 32; off; off >>= 1) sum += __shfl_xor(sum, off, 64);
        if (lane == 0) s_red[16 + wid] = sum;
        __syncthreads();
        float total = s_red[16 + rb];
        #pragma unroll
        for (int i2 = 1; i2 < 8; ++i2) total += s_red[16 + rb + i2];
        float a = e * __builtin_amdgcn_rcpf(total);
        _Float16 ah = (_Float16)a;
        uint_t ap = *(ushort_t*)&ah;
        s_al2[tid & 511][t_loc] = ap | (ap << 16);   // 0 past len
    }
    __syncthreads();

    const int ng = tid & 127, sq = tid >> 7;      // sq 0..7
    const int n0 = ng * 4;
    const int sbeg = sq * 64;
    float fo0[4] = {0.f, 0.f, 0.f, 0.f};
    float fo1[4] = {0.f, 0.f, 0.f, 0.f};
    {
        const ushort_t* ew = (const ushort_t*)encWo + ((size_t)b * SS + sbeg) * HD + n0;
        const int rem = (len > sbeg) ? ((len - sbeg < 64) ? len - sbeg : 64) : 0;
        const int schunks = (rem + 7) >> 3;       // alpha==0 past len -> full chunks safe
        for (int c = 0; c < schunks; ++c) {
            half2_t a01_0, a23_0, a01_1, a23_1;
            a01_0[0] = (_Float16)0.f; a01_0[1] = (_Float16)0.f;
            a23_0 = a01_0; a01_1 = a01_0; a23_1 = a01_0;
            const ushort_t* ewc = ew + (size_t)(c * 8) * HD;
            #pragma unroll
            for (int k = 0; k < 8; ++k) {
                uint2 wv = *(const uint2*)(ewc + (size_t)k * HD);
                uint2 av = *(const uint2*)&s_al2[sbeg + c * 8 + k][0];
                half2_t w01 = *(half2_t*)&wv.x, w23 = *(half2_t*)&wv.y;
                half2_t al0 = *(half2_t*)&av.x, al1 = *(half2_t*)&av.y;
                a01_0 = al0 * w01 + a01_0; a23_0 = al0 * w23 + a23_0;
                a01_1 = al1 * w01 + a01_1; a23_1 = al1 * w23 + a23_1;
            }
            fo0[0] += (float)a01_0[0]; fo0[1] += (float)a01_0[1];
            fo0[2] += (float)a23_0[0]; fo0[3] += (float)a23_0[1];
            fo1[0] += (float)a01_1[0]; fo1[1] += (float)a01_1[1];
            fo1[2] += (float)a23_1[0]; fo1[3] += (float)a23_1[1];
        }
    }
    __syncthreads();                              // s_part reuse barrier
    {
        float4 w0; w0.x = fo0[0]; w0.y = fo0[1]; w0.z = fo0[2]; w0.w = fo0[3];
        float4 w1; w1.x = fo1[0]; w1.y = fo1[1]; w1.z = fo1[2]; w1.w = fo1[3];
        *(float4*)&s_part[sq][0][n0] = w0;
        *(float4*)&s_part[sq][1][n0] = w1;
    }
    __syncthreads();
    {
        const int t_loc = tid >> 9, n = tid & 511;
        float acc = 0.f;
        #pragma unroll
        for (int q = 0; q < 8; ++q) acc += s_part[q][t_loc][n];
        acc += qWob[(size_t)(bt0 + t_loc) * HD + n];
        out[(size_t)(bt0 + t_loc) * HD + n] = tanh_e(acc);
    }
}

extern "C" void kernel_launch(void* const* d_in, const int* in_sizes, int n_in,
                              void* d_out, int out_size, void* d_ws, size_t ws_size,
                              hipStream_t stream) {
    (void)in_sizes; (void)n_in; (void)out_size; (void)ws_size;
    const float* query = (const float*)d_in[0];   // (B,T,H)
    const float* enc   = (const float*)d_in[1];   // (B,S,H)
    const int*   lens  = (const int*)d_in[2];     // (B,)
    const float* W_h   = (const float*)d_in[3];   // (H,H)
    const float* W_s   = (const float*)d_in[4];   // (H,H)
    const float* v     = (const float*)d_in[5];   // (H,)
    const float* W_out = (const float*)d_in[6];   // (2H,H)
    float* out = (float*)d_out;

    // workspace layout (~7 MB)
    float2*   tqa   = (float2*)d_ws;                            // 2 MB {tanh(pq), v*tanh(pq)}
    _Float16* peT   = (_Float16*)(tqa + (size_t)BB * TT * HD);  // 2 MB fp16 tanh(pe)^T
    _Float16* encWo = peT + (size_t)BB * HD * SS;               // 2 MB fp16 enc@Wo_a
    float*    qWob  = (float*)(encWo + (size_t)BB * SS * HD);   // 1 MB fp32 q@Wo_b

    proj_kernel<<<dim3(80, 8), 256, 0, stream>>>(query, enc, W_s, W_h, W_out, v,
                                                 tqa, peT, encWo, qWob);
    fused_kernel<<<dim3(BB * TT / 2), 1024, 0, stream>>>(tqa, peT, v, encWo, qWob, lens, out);
}